// Round 29
// baseline (73.644 us; speedup 1.0000x reference)
//
#include <hip/hip_runtime.h>
#include <math.h>

// Canny filter, fully fused single-pass kernel. PASSED r18 numerics preserved
// bit-exactly. r29 = r28 + mag8 kept in registers (ONLY -- r27's spill came
// from mag8 COMBINED with ~30 live packed-prep temps; VGPR now 32/64 so +8
// is safe). Stage 5 compare operand in-register; 8 lane-local ds_reads and
// their address chains removed. Spill check: WRITE_SIZE must stay ~61MB.
// All decision logic and per-pixel op orders verbatim => output bit-identical.
//
// LDS (f32): s_tmp(72x68) -> s_blur(68x68); s_mag(66x66) overlays s_tmp.

#define BXT 64
#define BYT 64
#define NT 512
#define HALO 4
#define TMP_W (BXT + 4)        // 68
#define TMP_H (BYT + 8)        // 72
#define BLUR_W (BXT + 4)       // 68
#define BLUR_H (BYT + 4)       // 68
#define MAG_W (BXT + 2)        // 66
#define MAG_H (BYT + 2)        // 66

#define ULP_BAND 1 // max integer-f32-ulp distance of o45 from a half-integer boundary

typedef float f32x2 __attribute__((ext_vector_type(2)));
typedef float f32x4 __attribute__((ext_vector_type(4)));

__device__ __forceinline__ f32x2 pk_mul(f32x2 a, f32x2 b)
{
    f32x2 d;
    asm("v_pk_mul_f32 %0, %1, %2" : "=v"(d) : "v"(a), "v"(b));
    return d;
}
__device__ __forceinline__ f32x2 pk_add(f32x2 a, f32x2 b)
{
    f32x2 d;
    asm("v_pk_add_f32 %0, %1, %2" : "=v"(d) : "v"(a), "v"(b));
    return d;
}

__global__ __launch_bounds__(512, 8) void canny_fused_kernel(
    const float* __restrict__ img,
    const float* __restrict__ wgh,
    const float* __restrict__ wgv,
    const float* __restrict__ wsh,
    const float* __restrict__ wsv,
    float* __restrict__ out,
    int H, int W, int C)
{
    __shared__ float s_tmp[TMP_H][TMP_W];
    __shared__ float s_blur[BLUR_H][BLUR_W];

    // s_mag overlays s_tmp (dead after stage 3): 66*66=4356 <= 72*68=4896.
    float* s_magp = &s_tmp[0][0];
    float* sf_tmp = &s_tmp[0][0];
    float* sf_blur = &s_blur[0][0];

    const int tid = threadIdx.x;
    const int tx = tid & 63;
    const int ty = tid >> 6; // 0..7

    const int x0 = blockIdx.x * BXT;
    const int y0 = blockIdx.y * BYT;
    const int bc = blockIdx.z; // b*C + c
    const int c = bc % C;

    const float* im = img + (size_t)bc * H * W;
    float* op = out + (size_t)bc * H * W;

    float gh[5], gv[5];
#pragma unroll
    for (int k = 0; k < 5; ++k) {
        gh[k] = wgh[c * 5 + k];
        gv[k] = wgv[c * 5 + k];
    }
    float sh[9], sv[9];
#pragma unroll
    for (int k = 0; k < 9; ++k) {
        sh[k] = wsh[c * 9 + k];
        sv[k] = wsv[c * 9 + k];
    }

    const bool interior = (x0 >= HALO) && (x0 + BXT + HALO <= W) &&
                          (y0 >= HALO) && (y0 + BYT + HALO <= H);

    // Stages 1+2 fused and stage 3: CHK literal 0/1; widths % 4 == 0.
#define DO_STAGES(CHK)                                                        \
    /* stage 1+2: h-gaussian from global loads (img elems 0-padded outside) */\
    {                                                                         \
        f32x2 gh2[5];                                                         \
        _Pragma("unroll")                                                     \
        for (int k = 0; k < 5; ++k) { gh2[k].x = gh[k]; gh2[k].y = gh[k]; }   \
        for (int e = tid * 4; e < TMP_H * TMP_W; e += NT * 4) {               \
            const int rr = e / TMP_W, cc = e - rr * TMP_W;                    \
            const int iy = y0 - HALO + rr;                                    \
            const int ixb = x0 - HALO + cc;                                   \
            float v[8];                                                       \
            if (!(CHK)) {                                                     \
                const long base = (long)iy * W + ixb;                         \
                const f32x4 a4 = *(const f32x4*)&im[base];                    \
                const f32x4 b4 = *(const f32x4*)&im[base + 4];                \
                v[0] = a4.x; v[1] = a4.y; v[2] = a4.z; v[3] = a4.w;           \
                v[4] = b4.x; v[5] = b4.y; v[6] = b4.z; v[7] = b4.w;           \
            } else {                                                          \
                const long base = (long)iy * W;                               \
                _Pragma("unroll")                                             \
                for (int j = 0; j < 8; ++j) {                                 \
                    const int ix = ixb + j;                                   \
                    v[j] = (iy >= 0 && iy < H && ix >= 0 && ix < W)           \
                               ? im[base + ix] : 0.0f;                        \
                }                                                             \
            }                                                                 \
            f32x2 a0 = {0.0f, 0.0f}, a1 = {0.0f, 0.0f};                       \
            _Pragma("unroll")                                                 \
            for (int k = 0; k < 5; ++k) {                                     \
                f32x2 p0, p1;                                                 \
                p0.x = v[k]; p0.y = v[k + 1];                                 \
                p1.x = v[k + 2]; p1.y = v[k + 3];                             \
                a0 = pk_add(a0, pk_mul(p0, gh2[k]));                          \
                a1 = pk_add(a1, pk_mul(p1, gh2[k]));                          \
            }                                                                 \
            f32x4 o4; o4.x = a0.x; o4.y = a0.y; o4.z = a1.x; o4.w = a1.y;     \
            *(f32x4*)&sf_tmp[e] = o4;                                         \
        }                                                                     \
    }                                                                         \
    __syncthreads();                                                          \
    /* stage 3: vertical gaussian (5x1), packed, zero outside image */        \
    {                                                                         \
        f32x2 gv2[5];                                                         \
        _Pragma("unroll")                                                     \
        for (int k = 0; k < 5; ++k) { gv2[k].x = gv[k]; gv2[k].y = gv[k]; }   \
        for (int e = tid * 4; e < BLUR_H * BLUR_W; e += NT * 4) {             \
            const int rr = e / BLUR_W, cc = e - rr * BLUR_W;                  \
            f32x2 a0 = {0.0f, 0.0f}, a1 = {0.0f, 0.0f};                       \
            _Pragma("unroll")                                                 \
            for (int k = 0; k < 5; ++k) {                                     \
                f32x2 p0, p1;                                                 \
                p0.x = s_tmp[rr + k][cc]; p0.y = s_tmp[rr + k][cc + 1];       \
                p1.x = s_tmp[rr + k][cc + 2]; p1.y = s_tmp[rr + k][cc + 3];   \
                a0 = pk_add(a0, pk_mul(p0, gv2[k]));                          \
                a1 = pk_add(a1, pk_mul(p1, gv2[k]));                          \
            }                                                                 \
            f32x4 o4; o4.x = a0.x; o4.y = a0.y; o4.z = a1.x; o4.w = a1.y;     \
            if (CHK) {                                                        \
                const int iy = y0 - 2 + rr, ix = x0 - 2 + cc;                 \
                if (!(iy >= 0 && iy < H)) {                                   \
                    o4.x = o4.y = o4.z = o4.w = 0.0f;                         \
                } else {                                                      \
                    if (!(ix >= 0 && ix < W)) o4.x = 0.0f;                    \
                    if (!(ix + 1 >= 0 && ix + 1 < W)) o4.y = 0.0f;            \
                    if (!(ix + 2 >= 0 && ix + 2 < W)) o4.z = 0.0f;            \
                    if (!(ix + 3 >= 0 && ix + 3 < W)) o4.w = 0.0f;            \
                }                                                             \
            }                                                                 \
            *(f32x4*)&sf_blur[e] = o4;                                        \
        }                                                                     \
    }                                                                         \
    __syncthreads();

    if (interior) {
        DO_STAGES(0)
    } else {
        DO_STAGES(1)
    }
#undef DO_STAGES

    // ---- stage 4: sobel (zero-skip) + CR f32 hypot ----
    // gx skips taps 1,4,7 (col 1); gy skips taps 3,4,5 (row 1). RN identity.
    // part A: own center pixels (rows ty+8q+1, q=0..7), pairs (q=p, q=p+4).
    float gx8[8], gy8[8], mag8[8];
    {
        f32x2 sh2[9], sv2[9];
#pragma unroll
        for (int k = 0; k < 9; ++k) {
            sh2[k].x = sh[k]; sh2[k].y = sh[k];
            sv2[k].x = sv[k]; sv2[k].y = sv[k];
        }
#pragma unroll
        for (int p = 0; p < 4; ++p) {
            const int rA = ty + 8 * p;      // q = p
            const int rB = rA + 32;         // q = p + 4
            f32x2 v[9];
#pragma unroll
            for (int ii = 0; ii < 3; ++ii) {
#pragma unroll
                for (int jj = 0; jj < 3; ++jj) {
                    if (ii == 1 && jj == 1) continue; // tap 4 unused by both
                    v[ii * 3 + jj].x = s_blur[rA + 1 + ii][tx + 1 + jj];
                    v[ii * 3 + jj].y = s_blur[rB + 1 + ii][tx + 1 + jj];
                }
            }
            f32x2 gxv = {0.0f, 0.0f}, gyv = {0.0f, 0.0f};
            gxv = pk_add(gxv, pk_mul(v[0], sh2[0]));
            gxv = pk_add(gxv, pk_mul(v[2], sh2[2]));
            gxv = pk_add(gxv, pk_mul(v[3], sh2[3]));
            gxv = pk_add(gxv, pk_mul(v[5], sh2[5]));
            gxv = pk_add(gxv, pk_mul(v[6], sh2[6]));
            gxv = pk_add(gxv, pk_mul(v[8], sh2[8]));
            gyv = pk_add(gyv, pk_mul(v[0], sv2[0]));
            gyv = pk_add(gyv, pk_mul(v[1], sv2[1]));
            gyv = pk_add(gyv, pk_mul(v[2], sv2[2]));
            gyv = pk_add(gyv, pk_mul(v[6], sv2[6]));
            gyv = pk_add(gyv, pk_mul(v[7], sv2[7]));
            gyv = pk_add(gyv, pk_mul(v[8], sv2[8]));

            const float mA = (float)sqrt((double)gxv.x * (double)gxv.x +
                                         (double)gyv.x * (double)gyv.x);
            const float mB = (float)sqrt((double)gxv.y * (double)gxv.y +
                                         (double)gyv.y * (double)gyv.y);
            gx8[p] = gxv.x; gx8[p + 4] = gxv.y;
            gy8[p] = gyv.x; gy8[p + 4] = gyv.y;
            mag8[p] = mA;   mag8[p + 4] = mB;
            s_magp[(rA + 1) * MAG_W + (tx + 1)] = mA;
            s_magp[(rB + 1) * MAG_W + (tx + 1)] = mB;
        }
    }
    // part B: mag halo ring (260 px), scalar zero-skip, zero-forced outside.
    if (tid < 260) {
        int rr, cc;
        if (tid < 66) { rr = 0; cc = tid; }
        else if (tid < 132) { rr = 65; cc = tid - 66; }
        else if (tid < 196) { rr = 1 + (tid - 132); cc = 0; }
        else { rr = 1 + (tid - 196); cc = 65; }
        const int iy = y0 - 1 + rr, ix = x0 - 1 + cc;
        float m = 0.0f;
        if (interior || (iy >= 0 && iy < H && ix >= 0 && ix < W)) {
            float b[9];
#pragma unroll
            for (int ii = 0; ii < 3; ++ii)
#pragma unroll
                for (int jj = 0; jj < 3; ++jj)
                    b[ii * 3 + jj] = s_blur[rr + ii][cc + jj];
            float gx = 0.0f, gy = 0.0f;
            gx = __fadd_rn(gx, __fmul_rn(b[0], sh[0]));
            gx = __fadd_rn(gx, __fmul_rn(b[2], sh[2]));
            gx = __fadd_rn(gx, __fmul_rn(b[3], sh[3]));
            gx = __fadd_rn(gx, __fmul_rn(b[5], sh[5]));
            gx = __fadd_rn(gx, __fmul_rn(b[6], sh[6]));
            gx = __fadd_rn(gx, __fmul_rn(b[8], sh[8]));
            gy = __fadd_rn(gy, __fmul_rn(b[0], sv[0]));
            gy = __fadd_rn(gy, __fmul_rn(b[1], sv[1]));
            gy = __fadd_rn(gy, __fmul_rn(b[2], sv[2]));
            gy = __fadd_rn(gy, __fmul_rn(b[6], sv[6]));
            gy = __fadd_rn(gy, __fmul_rn(b[7], sv[7]));
            gy = __fadd_rn(gy, __fmul_rn(b[8], sv[8]));
            m = (float)sqrt((double)gx * (double)gx + (double)gy * (double)gy);
        }
        s_magp[rr * MAG_W + cc] = m;
    }
    __syncthreads();

    // ---- stage 5: sector (fast ratio tests / exact fallback) + NMS ----
    const float R32 = (float)(180.0 / M_PI); // 57.29578f
#pragma unroll
    for (int q = 0; q < 8; ++q) {
        const int r = ty + 8 * q; // 0..63
        const int oy = y0 + r;
        const int ox = x0 + tx;
        const int cbase = (r + 1) * MAG_W + (tx + 1);

        const float gx = gx8[q];
        const float gy = gy8[q];
        const float mag = mag8[q];

        // strict NMS decision as a function of sector t (exact path)
        auto keep_for = [&](int s) -> bool {
            const int ipq = s & 7;
            if (ipq >= 4) return true;
            const int dy = (ipq != 0) ? 1 : 0;
            const int dx = 1 - ((ipq >= 2) ? (ipq - 1) : 0);
            const float n1 = s_magp[(r + 1 + dy) * MAG_W + (tx + 1 + dx)];
            const float n2 = s_magp[(r + 1 - dy) * MAG_W + (tx + 1 - dx)];
            return (mag > n1) && (mag > n2); // strict, like min(d1,d2)>0
        };

        // ---- fast sector classification (f32 ratio tests, 1e-5 guard) ----
        const float T1f = 0.41421356f; // ~tan(22.5)
        const float T3f = 2.41421356f; // ~tan(67.5)
        const float ax = fabsf(gx), ay = fabsf(gy);
        const float b1 = T1f * ax, b3 = T3f * ax;
        const float g1 = 1e-5f * b1, g3 = 1e-5f * b3;

        int region = -1; // 0: |r|<T1, 1: T1<|r|<T3, 2: |r|>T3; -1: fallback
        if (ay < b1 - g1) region = 0;
        else if (ay > b1 + g1 && ay < b3 - g3) region = 1;
        else if (ay > b3 + g3) region = 2;

        bool keep;
        if (region >= 0) {
            // sector from signs + region; provably out-of-band
            int t;
            const bool xp = (gx > 0.0f);
            if (gy < 0.0f)
                t = xp ? (region == 0 ? 4 : (region == 1 ? 3 : 2))
                       : (region == 0 ? 0 : (region == 1 ? 1 : 2));
            else
                t = xp ? (region == 0 ? 4 : (region == 1 ? 5 : 6))
                       : (region == 0 ? 8 : (region == 1 ? 7 : 6));
            const int ip = t & 7;
            if (ip >= 4) {
                keep = true;
            } else {
                const int off = (ip == 0) ? 1
                              : (ip == 1) ? (MAG_W + 1)
                              : (ip == 2) ? MAG_W : (MAG_W - 1);
                const float n1 = s_magp[cbase + off];
                const float n2 = s_magp[cbase - off];
                keep = (mag > n1) && (mag > n2);
            }
        } else {
            // ---- exact r18 path (verbatim) ----
            const float a32 = (float)atan2((double)gy, (double)gx);
            const float o = __fadd_rn(__fmul_rn(a32, R32), 180.0f);
            const float o45 = __fdiv_rn(o, 45.0f); // in [0, 8]

            const float fl = floorf(o45);
            const int bi = (int)fl;              // boundary b = bi + 0.5
            const float bval = fl + 0.5f;        // exactly representable
            const int du = abs(__float_as_int(o45) - __float_as_int(bval));
            if (du <= ULP_BAND && o45 <= bval && bi >= 0 && bi <= 7) {
                const bool k_lo = keep_for(bi);
                const bool k_hi = keep_for(bi + 1);
                if (k_lo == k_hi) {
                    keep = k_lo; // agree: decision independent of the flip
                } else {
                    // sigma-directed: np's atan2f error points up iff gx*gy>0
                    const bool sig_pos =
                        (((__float_as_int(gx) ^ __float_as_int(gy)) >> 31) & 1) == 0;
                    keep = sig_pos ? k_hi : k_lo;
                }
            } else {
                keep = keep_for((int)rintf(o45)); // out-of-band: rint
            }
        }

        op[(size_t)oy * W + ox] = keep ? mag : 0.0f;
    }
}

extern "C" void kernel_launch(void* const* d_in, const int* in_sizes, int n_in,
                              void* d_out, int out_size, void* d_ws, size_t ws_size,
                              hipStream_t stream)
{
    const float* img = (const float*)d_in[0];
    const float* wgh = (const float*)d_in[1];
    const float* wgv = (const float*)d_in[2];
    const float* wsh = (const float*)d_in[3];
    const float* wsv = (const float*)d_in[4];
    // d_in[5] = w_dir: directional conv == mag[center]-mag[neighbor] (weights +-1/0)

    const int B = 16, C = 3, H = 512, W = 512;
    (void)in_sizes; (void)n_in; (void)out_size; (void)d_ws; (void)ws_size;

    dim3 grid(W / BXT, H / BYT, B * C);
    dim3 block(NT);
    hipLaunchKernelGGL(canny_fused_kernel, grid, block, 0, stream,
                       img, wgh, wgv, wsh, wsv, (float*)d_out, H, W, C);
}

// Round 30
// 59.397 us; speedup vs baseline: 1.2399x; 1.2399x over previous
//
#include <hip/hip_runtime.h>
#include <math.h>

// Canny filter, fully fused single-pass kernel. PASSED r18 numerics preserved
// bit-exactly. r30 = r28 VERBATIM (known-good 59.7us). r29's lesson: with a
// third 8-elem array (mag8) live into stage 5, the compiler stops fully
// unrolling the q-loop -> ALL per-q arrays become runtime-indexed -> scratch
// (WRITE_SIZE 61->233MB, VGPR shows 32 because nothing is in registers).
// Stage-5 register placement is a cliff; r28's two-array form is the optimum
// found. Decision logic and per-pixel op order: r18-exact, bit-identical.
//
// LDS (f32): s_tmp(72x68) -> s_blur(68x68); s_mag(66x66) overlays s_tmp.

#define BXT 64
#define BYT 64
#define NT 512
#define HALO 4
#define TMP_W (BXT + 4)        // 68
#define TMP_H (BYT + 8)        // 72
#define BLUR_W (BXT + 4)       // 68
#define BLUR_H (BYT + 4)       // 68
#define MAG_W (BXT + 2)        // 66
#define MAG_H (BYT + 2)        // 66

#define ULP_BAND 1 // max integer-f32-ulp distance of o45 from a half-integer boundary

typedef float f32x2 __attribute__((ext_vector_type(2)));
typedef float f32x4 __attribute__((ext_vector_type(4)));

__device__ __forceinline__ f32x2 pk_mul(f32x2 a, f32x2 b)
{
    f32x2 d;
    asm("v_pk_mul_f32 %0, %1, %2" : "=v"(d) : "v"(a), "v"(b));
    return d;
}
__device__ __forceinline__ f32x2 pk_add(f32x2 a, f32x2 b)
{
    f32x2 d;
    asm("v_pk_add_f32 %0, %1, %2" : "=v"(d) : "v"(a), "v"(b));
    return d;
}

__global__ __launch_bounds__(512, 8) void canny_fused_kernel(
    const float* __restrict__ img,
    const float* __restrict__ wgh,
    const float* __restrict__ wgv,
    const float* __restrict__ wsh,
    const float* __restrict__ wsv,
    float* __restrict__ out,
    int H, int W, int C)
{
    __shared__ float s_tmp[TMP_H][TMP_W];
    __shared__ float s_blur[BLUR_H][BLUR_W];

    // s_mag overlays s_tmp (dead after stage 3): 66*66=4356 <= 72*68=4896.
    float* s_magp = &s_tmp[0][0];
    float* sf_tmp = &s_tmp[0][0];
    float* sf_blur = &s_blur[0][0];

    const int tid = threadIdx.x;
    const int tx = tid & 63;
    const int ty = tid >> 6; // 0..7

    const int x0 = blockIdx.x * BXT;
    const int y0 = blockIdx.y * BYT;
    const int bc = blockIdx.z; // b*C + c
    const int c = bc % C;

    const float* im = img + (size_t)bc * H * W;
    float* op = out + (size_t)bc * H * W;

    float gh[5], gv[5];
#pragma unroll
    for (int k = 0; k < 5; ++k) {
        gh[k] = wgh[c * 5 + k];
        gv[k] = wgv[c * 5 + k];
    }
    float sh[9], sv[9];
#pragma unroll
    for (int k = 0; k < 9; ++k) {
        sh[k] = wsh[c * 9 + k];
        sv[k] = wsv[c * 9 + k];
    }

    const bool interior = (x0 >= HALO) && (x0 + BXT + HALO <= W) &&
                          (y0 >= HALO) && (y0 + BYT + HALO <= H);

    // Stages 1+2 fused and stage 3: CHK literal 0/1; widths % 4 == 0.
#define DO_STAGES(CHK)                                                        \
    /* stage 1+2: h-gaussian from global loads (img elems 0-padded outside) */\
    {                                                                         \
        f32x2 gh2[5];                                                         \
        _Pragma("unroll")                                                     \
        for (int k = 0; k < 5; ++k) { gh2[k].x = gh[k]; gh2[k].y = gh[k]; }   \
        for (int e = tid * 4; e < TMP_H * TMP_W; e += NT * 4) {               \
            const int rr = e / TMP_W, cc = e - rr * TMP_W;                    \
            const int iy = y0 - HALO + rr;                                    \
            const int ixb = x0 - HALO + cc;                                   \
            float v[8];                                                       \
            if (!(CHK)) {                                                     \
                const long base = (long)iy * W + ixb;                         \
                const f32x4 a4 = *(const f32x4*)&im[base];                    \
                const f32x4 b4 = *(const f32x4*)&im[base + 4];                \
                v[0] = a4.x; v[1] = a4.y; v[2] = a4.z; v[3] = a4.w;           \
                v[4] = b4.x; v[5] = b4.y; v[6] = b4.z; v[7] = b4.w;           \
            } else {                                                          \
                const long base = (long)iy * W;                               \
                _Pragma("unroll")                                             \
                for (int j = 0; j < 8; ++j) {                                 \
                    const int ix = ixb + j;                                   \
                    v[j] = (iy >= 0 && iy < H && ix >= 0 && ix < W)           \
                               ? im[base + ix] : 0.0f;                        \
                }                                                             \
            }                                                                 \
            f32x2 a0 = {0.0f, 0.0f}, a1 = {0.0f, 0.0f};                       \
            _Pragma("unroll")                                                 \
            for (int k = 0; k < 5; ++k) {                                     \
                f32x2 p0, p1;                                                 \
                p0.x = v[k]; p0.y = v[k + 1];                                 \
                p1.x = v[k + 2]; p1.y = v[k + 3];                             \
                a0 = pk_add(a0, pk_mul(p0, gh2[k]));                          \
                a1 = pk_add(a1, pk_mul(p1, gh2[k]));                          \
            }                                                                 \
            f32x4 o4; o4.x = a0.x; o4.y = a0.y; o4.z = a1.x; o4.w = a1.y;     \
            *(f32x4*)&sf_tmp[e] = o4;                                         \
        }                                                                     \
    }                                                                         \
    __syncthreads();                                                          \
    /* stage 3: vertical gaussian (5x1), packed, zero outside image */        \
    {                                                                         \
        f32x2 gv2[5];                                                         \
        _Pragma("unroll")                                                     \
        for (int k = 0; k < 5; ++k) { gv2[k].x = gv[k]; gv2[k].y = gv[k]; }   \
        for (int e = tid * 4; e < BLUR_H * BLUR_W; e += NT * 4) {             \
            const int rr = e / BLUR_W, cc = e - rr * BLUR_W;                  \
            f32x2 a0 = {0.0f, 0.0f}, a1 = {0.0f, 0.0f};                       \
            _Pragma("unroll")                                                 \
            for (int k = 0; k < 5; ++k) {                                     \
                f32x2 p0, p1;                                                 \
                p0.x = s_tmp[rr + k][cc]; p0.y = s_tmp[rr + k][cc + 1];       \
                p1.x = s_tmp[rr + k][cc + 2]; p1.y = s_tmp[rr + k][cc + 3];   \
                a0 = pk_add(a0, pk_mul(p0, gv2[k]));                          \
                a1 = pk_add(a1, pk_mul(p1, gv2[k]));                          \
            }                                                                 \
            f32x4 o4; o4.x = a0.x; o4.y = a0.y; o4.z = a1.x; o4.w = a1.y;     \
            if (CHK) {                                                        \
                const int iy = y0 - 2 + rr, ix = x0 - 2 + cc;                 \
                if (!(iy >= 0 && iy < H)) {                                   \
                    o4.x = o4.y = o4.z = o4.w = 0.0f;                         \
                } else {                                                      \
                    if (!(ix >= 0 && ix < W)) o4.x = 0.0f;                    \
                    if (!(ix + 1 >= 0 && ix + 1 < W)) o4.y = 0.0f;            \
                    if (!(ix + 2 >= 0 && ix + 2 < W)) o4.z = 0.0f;            \
                    if (!(ix + 3 >= 0 && ix + 3 < W)) o4.w = 0.0f;            \
                }                                                             \
            }                                                                 \
            *(f32x4*)&sf_blur[e] = o4;                                        \
        }                                                                     \
    }                                                                         \
    __syncthreads();

    if (interior) {
        DO_STAGES(0)
    } else {
        DO_STAGES(1)
    }
#undef DO_STAGES

    // ---- stage 4: sobel (zero-skip) + CR f32 hypot ----
    // gx skips taps 1,4,7 (col 1); gy skips taps 3,4,5 (row 1). RN identity.
    // part A: own center pixels (rows ty+8q+1, q=0..7), pairs (q=p, q=p+4).
    float gx8[8], gy8[8];
    {
        f32x2 sh2[9], sv2[9];
#pragma unroll
        for (int k = 0; k < 9; ++k) {
            sh2[k].x = sh[k]; sh2[k].y = sh[k];
            sv2[k].x = sv[k]; sv2[k].y = sv[k];
        }
#pragma unroll
        for (int p = 0; p < 4; ++p) {
            const int rA = ty + 8 * p;      // q = p
            const int rB = rA + 32;         // q = p + 4
            f32x2 v[9];
#pragma unroll
            for (int ii = 0; ii < 3; ++ii) {
#pragma unroll
                for (int jj = 0; jj < 3; ++jj) {
                    if (ii == 1 && jj == 1) continue; // tap 4 unused by both
                    v[ii * 3 + jj].x = s_blur[rA + 1 + ii][tx + 1 + jj];
                    v[ii * 3 + jj].y = s_blur[rB + 1 + ii][tx + 1 + jj];
                }
            }
            f32x2 gxv = {0.0f, 0.0f}, gyv = {0.0f, 0.0f};
            gxv = pk_add(gxv, pk_mul(v[0], sh2[0]));
            gxv = pk_add(gxv, pk_mul(v[2], sh2[2]));
            gxv = pk_add(gxv, pk_mul(v[3], sh2[3]));
            gxv = pk_add(gxv, pk_mul(v[5], sh2[5]));
            gxv = pk_add(gxv, pk_mul(v[6], sh2[6]));
            gxv = pk_add(gxv, pk_mul(v[8], sh2[8]));
            gyv = pk_add(gyv, pk_mul(v[0], sv2[0]));
            gyv = pk_add(gyv, pk_mul(v[1], sv2[1]));
            gyv = pk_add(gyv, pk_mul(v[2], sv2[2]));
            gyv = pk_add(gyv, pk_mul(v[6], sv2[6]));
            gyv = pk_add(gyv, pk_mul(v[7], sv2[7]));
            gyv = pk_add(gyv, pk_mul(v[8], sv2[8]));

            const float mA = (float)sqrt((double)gxv.x * (double)gxv.x +
                                         (double)gyv.x * (double)gyv.x);
            const float mB = (float)sqrt((double)gxv.y * (double)gxv.y +
                                         (double)gyv.y * (double)gyv.y);
            gx8[p] = gxv.x; gx8[p + 4] = gxv.y;
            gy8[p] = gyv.x; gy8[p + 4] = gyv.y;
            s_magp[(rA + 1) * MAG_W + (tx + 1)] = mA;
            s_magp[(rB + 1) * MAG_W + (tx + 1)] = mB;
        }
    }
    // part B: mag halo ring (260 px), scalar zero-skip, zero-forced outside.
    if (tid < 260) {
        int rr, cc;
        if (tid < 66) { rr = 0; cc = tid; }
        else if (tid < 132) { rr = 65; cc = tid - 66; }
        else if (tid < 196) { rr = 1 + (tid - 132); cc = 0; }
        else { rr = 1 + (tid - 196); cc = 65; }
        const int iy = y0 - 1 + rr, ix = x0 - 1 + cc;
        float m = 0.0f;
        if (interior || (iy >= 0 && iy < H && ix >= 0 && ix < W)) {
            float b[9];
#pragma unroll
            for (int ii = 0; ii < 3; ++ii)
#pragma unroll
                for (int jj = 0; jj < 3; ++jj)
                    b[ii * 3 + jj] = s_blur[rr + ii][cc + jj];
            float gx = 0.0f, gy = 0.0f;
            gx = __fadd_rn(gx, __fmul_rn(b[0], sh[0]));
            gx = __fadd_rn(gx, __fmul_rn(b[2], sh[2]));
            gx = __fadd_rn(gx, __fmul_rn(b[3], sh[3]));
            gx = __fadd_rn(gx, __fmul_rn(b[5], sh[5]));
            gx = __fadd_rn(gx, __fmul_rn(b[6], sh[6]));
            gx = __fadd_rn(gx, __fmul_rn(b[8], sh[8]));
            gy = __fadd_rn(gy, __fmul_rn(b[0], sv[0]));
            gy = __fadd_rn(gy, __fmul_rn(b[1], sv[1]));
            gy = __fadd_rn(gy, __fmul_rn(b[2], sv[2]));
            gy = __fadd_rn(gy, __fmul_rn(b[6], sv[6]));
            gy = __fadd_rn(gy, __fmul_rn(b[7], sv[7]));
            gy = __fadd_rn(gy, __fmul_rn(b[8], sv[8]));
            m = (float)sqrt((double)gx * (double)gx + (double)gy * (double)gy);
        }
        s_magp[rr * MAG_W + cc] = m;
    }
    __syncthreads();

    // ---- stage 5: sector (fast ratio tests / exact fallback) + NMS ----
    const float R32 = (float)(180.0 / M_PI); // 57.29578f
#pragma unroll
    for (int q = 0; q < 8; ++q) {
        const int r = ty + 8 * q; // 0..63
        const int oy = y0 + r;
        const int ox = x0 + tx;
        const int cbase = (r + 1) * MAG_W + (tx + 1);

        const float gx = gx8[q];
        const float gy = gy8[q];
        const float mag = s_magp[cbase];

        // strict NMS decision as a function of sector t (exact path)
        auto keep_for = [&](int s) -> bool {
            const int ipq = s & 7;
            if (ipq >= 4) return true;
            const int dy = (ipq != 0) ? 1 : 0;
            const int dx = 1 - ((ipq >= 2) ? (ipq - 1) : 0);
            const float n1 = s_magp[(r + 1 + dy) * MAG_W + (tx + 1 + dx)];
            const float n2 = s_magp[(r + 1 - dy) * MAG_W + (tx + 1 - dx)];
            return (mag > n1) && (mag > n2); // strict, like min(d1,d2)>0
        };

        // ---- fast sector classification (f32 ratio tests, 1e-5 guard) ----
        const float T1f = 0.41421356f; // ~tan(22.5)
        const float T3f = 2.41421356f; // ~tan(67.5)
        const float ax = fabsf(gx), ay = fabsf(gy);
        const float b1 = T1f * ax, b3 = T3f * ax;
        const float g1 = 1e-5f * b1, g3 = 1e-5f * b3;

        int region = -1; // 0: |r|<T1, 1: T1<|r|<T3, 2: |r|>T3; -1: fallback
        if (ay < b1 - g1) region = 0;
        else if (ay > b1 + g1 && ay < b3 - g3) region = 1;
        else if (ay > b3 + g3) region = 2;

        bool keep;
        if (region >= 0) {
            // sector from signs + region; provably out-of-band
            int t;
            const bool xp = (gx > 0.0f);
            if (gy < 0.0f)
                t = xp ? (region == 0 ? 4 : (region == 1 ? 3 : 2))
                       : (region == 0 ? 0 : (region == 1 ? 1 : 2));
            else
                t = xp ? (region == 0 ? 4 : (region == 1 ? 5 : 6))
                       : (region == 0 ? 8 : (region == 1 ? 7 : 6));
            const int ip = t & 7;
            if (ip >= 4) {
                keep = true;
            } else {
                const int off = (ip == 0) ? 1
                              : (ip == 1) ? (MAG_W + 1)
                              : (ip == 2) ? MAG_W : (MAG_W - 1);
                const float n1 = s_magp[cbase + off];
                const float n2 = s_magp[cbase - off];
                keep = (mag > n1) && (mag > n2);
            }
        } else {
            // ---- exact r18 path (verbatim) ----
            const float a32 = (float)atan2((double)gy, (double)gx);
            const float o = __fadd_rn(__fmul_rn(a32, R32), 180.0f);
            const float o45 = __fdiv_rn(o, 45.0f); // in [0, 8]

            const float fl = floorf(o45);
            const int bi = (int)fl;              // boundary b = bi + 0.5
            const float bval = fl + 0.5f;        // exactly representable
            const int du = abs(__float_as_int(o45) - __float_as_int(bval));
            if (du <= ULP_BAND && o45 <= bval && bi >= 0 && bi <= 7) {
                const bool k_lo = keep_for(bi);
                const bool k_hi = keep_for(bi + 1);
                if (k_lo == k_hi) {
                    keep = k_lo; // agree: decision independent of the flip
                } else {
                    // sigma-directed: np's atan2f error points up iff gx*gy>0
                    const bool sig_pos =
                        (((__float_as_int(gx) ^ __float_as_int(gy)) >> 31) & 1) == 0;
                    keep = sig_pos ? k_hi : k_lo;
                }
            } else {
                keep = keep_for((int)rintf(o45)); // out-of-band: rint
            }
        }

        op[(size_t)oy * W + ox] = keep ? mag : 0.0f;
    }
}

extern "C" void kernel_launch(void* const* d_in, const int* in_sizes, int n_in,
                              void* d_out, int out_size, void* d_ws, size_t ws_size,
                              hipStream_t stream)
{
    const float* img = (const float*)d_in[0];
    const float* wgh = (const float*)d_in[1];
    const float* wgv = (const float*)d_in[2];
    const float* wsh = (const float*)d_in[3];
    const float* wsv = (const float*)d_in[4];
    // d_in[5] = w_dir: directional conv == mag[center]-mag[neighbor] (weights +-1/0)

    const int B = 16, C = 3, H = 512, W = 512;
    (void)in_sizes; (void)n_in; (void)out_size; (void)d_ws; (void)ws_size;

    dim3 grid(W / BXT, H / BYT, B * C);
    dim3 block(NT);
    hipLaunchKernelGGL(canny_fused_kernel, grid, block, 0, stream,
                       img, wgh, wgv, wsh, wsv, (float*)d_out, H, W, C);
}